// Round 1
// baseline (109.518 us; speedup 1.0000x reference)
//
#include <hip/hip_runtime.h>
#include <hip/hip_bf16.h>
#include <math.h>

// NTXent loss, N=8192 rows, D=128.
// loss = mean_i [ log(sum_{j!=i} exp(2*cos_ij)) - 2*cos_{i,partner} ]
// Fused GEMM(8192x8192x128, bf16 MFMA) + exp + row-sum; sim never materialized.

typedef __attribute__((ext_vector_type(8))) short bf16x8;   // 8 bf16 = 4 VGPRs
typedef __attribute__((ext_vector_type(4))) float f32x4;

#define NROWS 8192
#define DDIM  128
#define BHALF 4096
// exp(2x) = 2^(x * 2/ln2)
#define EXP2SCALE 2.8853900817779268f

static __device__ __forceinline__ unsigned short f2bf(float f) {
  unsigned int u = __float_as_uint(f);
  unsigned int r = (u + 0x7fffu + ((u >> 16) & 1u)) >> 16;   // RNE
  return (unsigned short)r;
}

// ---- Kernel 1: row-normalize into bf16, zero row_sums and out ------------
__global__ void norm_zero_kernel(const float* __restrict__ zi, const float* __restrict__ zj,
                                 unsigned short* __restrict__ zn,
                                 float* __restrict__ row_sums, float* __restrict__ out) {
  int wave = threadIdx.x >> 6;
  int lane = threadIdx.x & 63;
  int row  = blockIdx.x * 4 + wave;                 // grid 2048 * 4 waves = 8192 rows
  const float* src = (row < BHALF) ? (zi + (size_t)row * DDIM)
                                   : (zj + (size_t)(row - BHALF) * DDIM);
  float2 v = *(const float2*)(src + 2 * lane);
  float ss = v.x * v.x + v.y * v.y;
  #pragma unroll
  for (int off = 1; off < 64; off <<= 1) ss += __shfl_xor(ss, off);
  float scale = 1.0f / fmaxf(sqrtf(ss), 1e-8f);
  unsigned int lo = f2bf(v.x * scale);
  unsigned int hi = f2bf(v.y * scale);
  ((unsigned int*)(zn + (size_t)row * DDIM))[lane] = lo | (hi << 16);

  if (threadIdx.x < 4) row_sums[blockIdx.x * 4 + threadIdx.x] = 0.0f;
  if (blockIdx.x == 0 && threadIdx.x == 0) out[0] = 0.0f;
}

// ---- Kernel 2: fused sim + exp + row-sum ---------------------------------
// Block = 4 waves. Wave owns 128 rows (A frags in registers, loaded once).
// B frags streamed straight from global (zn is 2MB -> L2-resident per XCD).
// Block tile: 512 rows x 256 cols. Grid (16,32) = 512 blocks = 2 blocks/CU.
__global__ __launch_bounds__(256, 2)
void sim_kernel(const unsigned short* __restrict__ zn, float* __restrict__ row_sums) {
  const int wave = threadIdx.x >> 6;
  const int lane = threadIdx.x & 63;
  const int l15  = lane & 15;
  const int quad = lane >> 4;

  const int row_base = (blockIdx.x * 4 + wave) * 128;
  const int col_base = blockIdx.y * 256;

  // A fragments: A[m=l15][k=quad*8+j], 8 mi-tiles x 4 k-frags
  bf16x8 a[8][4];
  const unsigned short* abase = zn + (size_t)(row_base + l15) * DDIM + quad * 8;
  #pragma unroll
  for (int mi = 0; mi < 8; ++mi)
    #pragma unroll
    for (int kf = 0; kf < 4; ++kf)
      a[mi][kf] = *(const bf16x8*)(abase + mi * 16 * DDIM + kf * 32);

  float rs[8][4];
  #pragma unroll
  for (int mi = 0; mi < 8; ++mi)
    #pragma unroll
    for (int r = 0; r < 4; ++r) rs[mi][r] = 0.0f;

  const unsigned short* bptr = zn + (size_t)(col_base + l15) * DDIM + quad * 8;
  bf16x8 b[4], nb[4];
  #pragma unroll
  for (int kf = 0; kf < 4; ++kf) b[kf] = *(const bf16x8*)(bptr + kf * 32);

  for (int ni = 0; ni < 16; ++ni) {
    if (ni < 15) {                                 // prefetch next 16-col tile
      const unsigned short* np = bptr + 16 * DDIM;
      #pragma unroll
      for (int kf = 0; kf < 4; ++kf) nb[kf] = *(const bf16x8*)(np + kf * 32);
    }
    f32x4 acc[8];
    #pragma unroll
    for (int mi = 0; mi < 8; ++mi) {
      f32x4 z = {0.0f, 0.0f, 0.0f, 0.0f};
      acc[mi] = __builtin_amdgcn_mfma_f32_16x16x32_bf16(a[mi][0], b[0], z, 0, 0, 0);
    }
    #pragma unroll
    for (int kf = 1; kf < 4; ++kf)
      #pragma unroll
      for (int mi = 0; mi < 8; ++mi)
        acc[mi] = __builtin_amdgcn_mfma_f32_16x16x32_bf16(a[mi][kf], b[kf], acc[mi], 0, 0, 0);
    // exp + accumulate (diagonal included; subtracted as exp(2) in finalize)
    #pragma unroll
    for (int mi = 0; mi < 8; ++mi)
      #pragma unroll
      for (int r = 0; r < 4; ++r)
        rs[mi][r] += exp2f(acc[mi][r] * EXP2SCALE);
    #pragma unroll
    for (int kf = 0; kf < 4; ++kf) b[kf] = nb[kf];
    bptr += 16 * DDIM;
  }

  // C/D layout: col = l15, row = quad*4 + reg. Reduce the 16 cols per quad.
  #pragma unroll
  for (int mi = 0; mi < 8; ++mi)
    #pragma unroll
    for (int r = 0; r < 4; ++r) {
      float v = rs[mi][r];
      v += __shfl_xor(v, 1);
      v += __shfl_xor(v, 2);
      v += __shfl_xor(v, 4);
      v += __shfl_xor(v, 8);
      if (l15 == 0)
        atomicAdd(&row_sums[row_base + mi * 16 + quad * 4 + r], v);
    }
}

// ---- Kernel 3: positives + logs + mean -----------------------------------
__global__ void finalize_kernel(const unsigned short* __restrict__ zn,
                                const float* __restrict__ row_sums,
                                float* __restrict__ out) {
  int wave = threadIdx.x >> 6;
  int lane = threadIdx.x & 63;
  int i = blockIdx.x * 4 + wave;                   // grid 1024 * 4 = 4096 pairs
  int p = i + BHALF;
  unsigned int ua = ((const unsigned int*)(zn + (size_t)i * DDIM))[lane];
  unsigned int ub = ((const unsigned int*)(zn + (size_t)p * DDIM))[lane];
  float d = __uint_as_float(ua << 16) * __uint_as_float(ub << 16)
          + __uint_as_float(ua & 0xffff0000u) * __uint_as_float(ub & 0xffff0000u);
  #pragma unroll
  for (int off = 1; off < 64; off <<= 1) d += __shfl_xor(d, off);

  __shared__ float red[4];
  if (lane == 0) {
    const float EXPDIAG = 7.38905609893065f;       // exp(2): self-similarity term
    float si = row_sums[i] - EXPDIAG;
    float sp = row_sums[p] - EXPDIAG;
    red[wave] = logf(si) + logf(sp) - 4.0f * d;    // -pos_i - pos_p = -4*cos
  }
  __syncthreads();
  if (threadIdx.x == 0)
    atomicAdd(out, (red[0] + red[1] + red[2] + red[3]) * (1.0f / 8192.0f));
}

extern "C" void kernel_launch(void* const* d_in, const int* in_sizes, int n_in,
                              void* d_out, int out_size, void* d_ws, size_t ws_size,
                              hipStream_t stream) {
  const float* zi = (const float*)d_in[0];
  const float* zj = (const float*)d_in[1];
  unsigned short* zn = (unsigned short*)d_ws;                           // 8192*128 bf16 = 2 MB
  float* row_sums = (float*)((char*)d_ws + (size_t)NROWS * DDIM * 2);   // 8192 fp32
  float* out = (float*)d_out;

  norm_zero_kernel<<<2048, 256, 0, stream>>>(zi, zj, zn, row_sums, out);
  sim_kernel<<<dim3(16, 32), 256, 0, stream>>>(zn, row_sums);
  finalize_kernel<<<1024, 256, 0, stream>>>(zn, row_sums, out);
}